// Round 3
// baseline (210.240 us; speedup 1.0000x reference)
//
#include <hip/hip_runtime.h>

// x [32,64,64,64] f32, emb [64,1024] f32
// N = 131072 pixels, D = 64, K = 1024
// out = [ result: 8388608 f32 ][ argmin-as-f32: 131072 ]
//
// Round 7: same exact split-f16 MFMA chain per (px, k) as rounds 3-6
// (bit-identical dist + identical argmin scan order -> absmax 0.0), but
// M-SPLIT ACROSS WAVES instead of K-split:
//  - each wave owns 32 px x ALL 1024 k (t = 0..63). A-frags drop from
//    128 regs/wave to 32; best-state from 36 to 16; total ~110 regs ->
//    4 waves/SIMD (was hard-capped at 2). Rounds 5/6 proved density
//    doesn't move MfmaUtil (stuck 28%) while occupancy fell 29->20%:
//    the kernel is latency-bound; only more resident waves can fill
//    the dependent-MFMA + load-wait gaps.
//  - per-wave full-K ownership kills the cross-wave rbest/ridx merge:
//    LDS 41.5 -> 37.4 KB -> 4 blocks/CU.
//  - B is streamed from L2 per wave (4x traffic vs K-split, ~2.9 TB/s
//    per XCD at target speed - well under the 4.3 TB/s ceiling).

using half8 = __attribute__((ext_vector_type(8))) _Float16;
using half4 = __attribute__((ext_vector_type(4))) _Float16;
using f32x4 = __attribute__((ext_vector_type(4))) float;

#define XPITCH 72   // halfs per x-row in LDS: 64 + 8 pad

__global__ void prep_kernel(const float* __restrict__ emb,
                            float* __restrict__ e2,
                            _Float16* __restrict__ eTh,
                            _Float16* __restrict__ eTl) {
    int k = blockIdx.x * 64 + threadIdx.x;   // 16 blocks x 64
    float s = 0.f;
#pragma unroll
    for (int c = 0; c < 8; ++c) {
        half8 hv, lv;
#pragma unroll
        for (int j = 0; j < 8; ++j) {
            float v = emb[(c * 8 + j) * 1024 + k];   // coalesced across lanes
            s = fmaf(v, v, s);                       // ascending-d fmaf (exact
            _Float16 h = (_Float16)v;                //  order from round 1)
            hv[j] = h;
            lv[j] = (_Float16)(v - (float)h);        // exact residual
        }
        *(half8*)(eTh + k * 64 + c * 8) = hv;
        *(half8*)(eTl + k * 64 + c * 8) = lv;
    }
    e2[k] = s;
}

__launch_bounds__(256, 4)
__global__ void vq_kernel(const float* __restrict__ x,
                          const _Float16* __restrict__ eTh,
                          const _Float16* __restrict__ eTl,
                          const float* __restrict__ e2,
                          const float* __restrict__ emb,
                          float* __restrict__ outq,
                          float* __restrict__ outidx) {
    __shared__ _Float16 sxh[128 * XPITCH];
    __shared__ _Float16 sxl[128 * XPITCH];
    __shared__ int samin[128];

    const int tx = threadIdx.x;
    const int n0 = blockIdx.x * 128;
    const int bb = n0 >> 12;
    const int hw = n0 & 4095;
    const float* xbase = x + bb * 262144 + hw;

    // ---- stage x -> LDS [p][d] as f16 hi/lo: 128 px x 64 d -----------------
    {
        const int p     = tx & 127;             // lanes -> consecutive p
        const int dbase = (tx >> 7) << 5;       // 0 or 32
#pragma unroll
        for (int it = 0; it < 8; ++it) {
            int d0 = dbase + it * 4;
            float v0 = xbase[(d0 + 0) * 4096 + p];
            float v1 = xbase[(d0 + 1) * 4096 + p];
            float v2 = xbase[(d0 + 2) * 4096 + p];
            float v3 = xbase[(d0 + 3) * 4096 + p];
            _Float16 h0 = (_Float16)v0, h1 = (_Float16)v1,
                     h2 = (_Float16)v2, h3 = (_Float16)v3;
            half4 hv = {h0, h1, h2, h3};
            half4 lv = {(_Float16)(v0 - (float)h0), (_Float16)(v1 - (float)h1),
                        (_Float16)(v2 - (float)h2), (_Float16)(v3 - (float)h3)};
            *(half4*)(sxh + p * XPITCH + d0) = hv;
            *(half4*)(sxl + p * XPITCH + d0) = lv;
        }
    }
    __syncthreads();

    const int lane = tx & 63;
    const int w    = tx >> 6;
    const int r16  = lane & 15;
    const int q    = lane >> 4;
    const int pxb  = w << 5;                 // wave's 32-pixel base row

    // ---- A-fragments: 2 mt tiles x 2 k-halves, hi+lo (32 VGPRs) -----------
    half8 ah[2][2], al[2][2];
#pragma unroll
    for (int mt = 0; mt < 2; ++mt)
#pragma unroll
        for (int s = 0; s < 2; ++s) {
            ah[mt][s] = *(const half8*)(sxh + (pxb + mt * 16 + r16) * XPITCH + s * 32 + q * 8);
            al[mt][s] = *(const half8*)(sxl + (pxb + mt * 16 + r16) * XPITCH + s * 32 + q * 8);
        }
    asm volatile("" ::: "memory");   // keep the ds_reads hoisted out of the loop

    float best[8];
    int   bestt[8];
#pragma unroll
    for (int i = 0; i < 8; ++i) { best[i] = 3.4e38f; bestt[i] = 0; }

    // wave covers ALL k: k = t*16 + r16, t in [0,64)
    const _Float16* bhbase = eTh + r16 * 64 + q * 8;
    const _Float16* blbase = eTl + r16 * 64 + q * 8;
    const float*    e2base = e2 + r16;

    half8 pbh0, pbh1, pbl0, pbl1; float pe2;
    half8 qbh0, qbh1, qbl0, qbl1; float qe2;

#define LOADSET(BH0, BH1, BL0, BL1, E2V, TT)                                  \
    {                                                                         \
        const int off_ = (TT) << 10;  /* 16 k-rows * 64 halfs */              \
        BH0 = *(const half8*)(bhbase + off_);                                 \
        BH1 = *(const half8*)(bhbase + off_ + 32);                            \
        BL0 = *(const half8*)(blbase + off_);                                 \
        BL1 = *(const half8*)(blbase + off_ + 32);                            \
        E2V = e2base[(TT) << 4];                                              \
    }

#define COMPUTE(BH0, BH1, BL0, BL1, E2V, TT)                                  \
    {                                                                         \
        _Pragma("unroll")                                                     \
        for (int mt = 0; mt < 2; ++mt) {                                      \
            f32x4 a = {0.f, 0.f, 0.f, 0.f};                                   \
            a = __builtin_amdgcn_mfma_f32_16x16x32_f16(al[mt][0], BL0, a, 0, 0, 0); \
            a = __builtin_amdgcn_mfma_f32_16x16x32_f16(al[mt][1], BL1, a, 0, 0, 0); \
            a = __builtin_amdgcn_mfma_f32_16x16x32_f16(al[mt][0], BH0, a, 0, 0, 0); \
            a = __builtin_amdgcn_mfma_f32_16x16x32_f16(al[mt][1], BH1, a, 0, 0, 0); \
            a = __builtin_amdgcn_mfma_f32_16x16x32_f16(ah[mt][0], BL0, a, 0, 0, 0); \
            a = __builtin_amdgcn_mfma_f32_16x16x32_f16(ah[mt][1], BL1, a, 0, 0, 0); \
            a = __builtin_amdgcn_mfma_f32_16x16x32_f16(ah[mt][0], BH0, a, 0, 0, 0); \
            a = __builtin_amdgcn_mfma_f32_16x16x32_f16(ah[mt][1], BH1, a, 0, 0, 0); \
            _Pragma("unroll")                                                 \
            for (int rr = 0; rr < 4; ++rr) {                                  \
                float dist_ = fmaf(-2.f, a[rr], E2V);                         \
                const int i_ = mt * 4 + rr;                                   \
                if (dist_ < best[i_]) { best[i_] = dist_; bestt[i_] = (TT); } \
            }                                                                 \
        }                                                                     \
    }

    LOADSET(pbh0, pbh1, pbl0, pbl1, pe2, 0);
#pragma unroll 1
    for (int t = 0; t < 64; t += 2) {
        LOADSET(qbh0, qbh1, qbl0, qbl1, qe2, t + 1);
        COMPUTE(pbh0, pbh1, pbl0, pbl1, pe2, t);
        LOADSET(pbh0, pbh1, pbl0, pbl1, pe2, (t + 2) & 63);  // wrap: valid, unused at t=62
        COMPUTE(qbh0, qbh1, qbl0, qbl1, qe2, t + 1);
    }

    // ---- per-pixel argmin: reduce over the 16 lanes sharing a C-row --------
    // t ascending = k ascending within a lane's residue class; strict <
    // in the loop kept the earliest (smallest k). Cross-lane merge breaks
    // ties toward smaller k. Identical semantics to rounds 3-6.
#pragma unroll
    for (int mt = 0; mt < 2; ++mt)
#pragma unroll
        for (int rr = 0; rr < 4; ++rr) {
            const int i = mt * 4 + rr;
            float bv = best[i];
            int   bk = (bestt[i] << 4) + r16;
#pragma unroll
            for (int m = 1; m < 16; m <<= 1) {
                float ov = __shfl_xor(bv, m, 64);
                int   ok = __shfl_xor(bk, m, 64);
                if (ov < bv || (ov == bv && ok < bk)) { bv = ov; bk = ok; }
            }
            if (r16 == 0) {
                const int p = pxb + mt * 16 + q * 4 + rr;
                samin[p] = bk;
            }
        }
    __syncthreads();

    if (tx < 128) outidx[n0 + tx] = (float)samin[tx];

    // ---- gather exact fp32 codebook rows -> output, coalesced over p -------
    const int p = tx & 127;
    const int drow = tx >> 7;                 // 0 or 1
    const int amin = samin[p];
    float* obase = outq + bb * 262144 + hw + p;
#pragma unroll
    for (int it = 0; it < 32; ++it) {
        int d = (it << 1) + drow;
        obase[d * 4096] = emb[d * 1024 + amin];
    }
}

extern "C" void kernel_launch(void* const* d_in, const int* in_sizes, int n_in,
                              void* d_out, int out_size, void* d_ws, size_t ws_size,
                              hipStream_t stream) {
    const float* x   = (const float*)d_in[0];
    const float* emb = (const float*)d_in[1];
    float* outq   = (float*)d_out;
    float* outidx = outq + 8388608;            // 32*64*64*64

    float*    e2  = (float*)d_ws;                               // 4 KB
    _Float16* eTh = (_Float16*)((char*)d_ws + 4096);            // 128 KB
    _Float16* eTl = (_Float16*)((char*)d_ws + 4096 + 131072);   // 128 KB

    prep_kernel<<<16, 64, 0, stream>>>(emb, e2, eTh, eTl);
    vq_kernel<<<1024, 256, 0, stream>>>(x, eTh, eTl, e2, emb, outq, outidx);
}

// Round 4
// 178.709 us; speedup vs baseline: 1.1764x; 1.1764x over previous
//
#include <hip/hip_runtime.h>

// x [32,64,64,64] f32, emb [64,1024] f32
// N = 131072 pixels, D = 64, K = 1024
// out = [ result: 8388608 f32 ][ argmin-as-f32: 131072 ]
//
// Round 8: same split-f16 product math (ll,lh,hl,hh in fp32 MFMA accum,
// dist = fmaf(-2,dot,e2), strict-< ascending-k argmin), restructured:
//  - 32x32x16 MFMA: HALF the MFMA instructions for the same logical work
//    (2.10M vs 4.19M) at a better FLOP/cy rate.
//  - B staged in LDS via global_load_lds(16B), double-buffered, SHARED by
//    all 4 waves (4x less VMEM than per-wave streaming; R7 showed private
//    full-K streaming thrashes L1). Pre-swizzled global source + swizzled
//    ds_read_b128 (involution sigma(z)=z^(((z>>7)&7)<<4)).
//  - M-split: each wave owns 32 px x all 1024 k -> one f32x16 acc pair,
//    best-update VALU ~100 instr/iter (was ~650), no cross-wave merge.

using half8  = __attribute__((ext_vector_type(8))) _Float16;
using half4  = __attribute__((ext_vector_type(4))) _Float16;
using f32x16 = __attribute__((ext_vector_type(16))) float;

#define XPITCH 72   // halfs per x-row in LDS: 64 + 8 pad

__global__ void prep_kernel(const float* __restrict__ emb,
                            float* __restrict__ e2,
                            _Float16* __restrict__ eTh,
                            _Float16* __restrict__ eTl) {
    int k = blockIdx.x * 64 + threadIdx.x;   // 16 blocks x 64
    float s = 0.f;
#pragma unroll
    for (int c = 0; c < 8; ++c) {
        half8 hv, lv;
#pragma unroll
        for (int j = 0; j < 8; ++j) {
            float v = emb[(c * 8 + j) * 1024 + k];   // coalesced across lanes
            s = fmaf(v, v, s);                       // ascending-d fmaf
            _Float16 h = (_Float16)v;
            hv[j] = h;
            lv[j] = (_Float16)(v - (float)h);        // exact residual
        }
        *(half8*)(eTh + k * 64 + c * 8) = hv;
        *(half8*)(eTl + k * 64 + c * 8) = lv;
    }
    e2[k] = s;
}

__launch_bounds__(256, 2)
__global__ void vq_kernel(const float* __restrict__ x,
                          const _Float16* __restrict__ eTh,
                          const _Float16* __restrict__ eTl,
                          const float* __restrict__ e2,
                          const float* __restrict__ emb,
                          float* __restrict__ outq,
                          float* __restrict__ outidx) {
    __shared__ _Float16 sxh[128 * XPITCH];
    __shared__ _Float16 sxl[128 * XPITCH];
    __shared__ __align__(16) _Float16 sB[2][4096];  // [buf][h:2048 | l:2048]
    __shared__ int samin[128];

    const int tx = threadIdx.x;
    const int n0 = blockIdx.x * 128;
    const int bb = n0 >> 12;
    const int hw = n0 & 4095;
    const float* xbase = x + bb * 262144 + hw;

    // ---- stage x -> LDS [p][d] as f16 hi/lo: 128 px x 64 d -----------------
    {
        const int p     = tx & 127;
        const int dbase = (tx >> 7) << 5;       // 0 or 32
#pragma unroll
        for (int it = 0; it < 8; ++it) {
            int d0 = dbase + it * 4;
            float v0 = xbase[(d0 + 0) * 4096 + p];
            float v1 = xbase[(d0 + 1) * 4096 + p];
            float v2 = xbase[(d0 + 2) * 4096 + p];
            float v3 = xbase[(d0 + 3) * 4096 + p];
            _Float16 h0 = (_Float16)v0, h1 = (_Float16)v1,
                     h2 = (_Float16)v2, h3 = (_Float16)v3;
            half4 hv = {h0, h1, h2, h3};
            half4 lv = {(_Float16)(v0 - (float)h0), (_Float16)(v1 - (float)h1),
                        (_Float16)(v2 - (float)h2), (_Float16)(v3 - (float)h3)};
            *(half4*)(sxh + p * XPITCH + d0) = hv;
            *(half4*)(sxl + p * XPITCH + d0) = lv;
        }
    }
    __syncthreads();

    const int lane = tx & 63;
    const int w    = tx >> 6;
    const int c    = lane & 31;    // 32x32 col / A-row
    const int hi   = lane >> 5;    // k-half selector
    const int pxb  = w << 5;       // wave's 32-pixel base

    // ---- A-fragments: row = c, d = ch*16 + hi*8 + j  (64 regs h+l) ---------
    half8 ah[4], al[4];
#pragma unroll
    for (int ch = 0; ch < 4; ++ch) {
        ah[ch] = *(const half8*)(sxh + (pxb + c) * XPITCH + ch * 16 + hi * 8);
        al[ch] = *(const half8*)(sxl + (pxb + c) * XPITCH + ch * 16 + hi * 8);
    }
    asm volatile("" ::: "memory");

    // ---- swizzled LDS read offsets for B (invariant over t) ----------------
    int Dofs[4];
#pragma unroll
    for (int ch = 0; ch < 4; ++ch) {
        const int y = c * 128 + ch * 32 + hi * 16;
        Dofs[ch] = y ^ ((c & 7) << 4);
    }

    // ---- staging source: pre-swizzled per-thread global byte offset --------
    const int Lb = tx * 16;                        // linear byte in 4KB tile
    const int Sb = Lb ^ (((Lb >> 7) & 7) << 4);    // sigma (self-inverse)
    const char* gH = (const char*)eTh + Sb;
    const char* gL = (const char*)eTl + Sb;

#define STAGE(BUF, TT)                                                        \
    {                                                                         \
        __builtin_amdgcn_global_load_lds(                                     \
            (const __attribute__((address_space(1))) unsigned int*)(gH + ((TT) << 12)), \
            (__attribute__((address_space(3))) unsigned int*)(sB[BUF] + (w << 9)),       \
            16, 0, 0);                                                        \
        __builtin_amdgcn_global_load_lds(                                     \
            (const __attribute__((address_space(1))) unsigned int*)(gL + ((TT) << 12)), \
            (__attribute__((address_space(3))) unsigned int*)(sB[BUF] + 2048 + (w << 9)),\
            16, 0, 0);                                                        \
    }

    float best[16];
    int   bestt[16];
#pragma unroll
    for (int i = 0; i < 16; ++i) { best[i] = 3.4e38f; bestt[i] = 0; }

    STAGE(0, 0);
    __syncthreads();   // drains vmcnt(0): buf0 ready

#pragma unroll 1
    for (int t = 0; t < 32; ++t) {
        const int cur = t & 1;
        if (t < 31) STAGE(cur ^ 1, t + 1);        // prefetch next tile

        const float e2v = e2[(t << 5) + c];
        const char* bbase = (const char*)sB[cur];
        half8 bh_[4], bl_[4];
#pragma unroll
        for (int ch = 0; ch < 4; ++ch) {
            bh_[ch] = *(const half8*)(bbase + Dofs[ch]);
            bl_[ch] = *(const half8*)(bbase + 4096 + Dofs[ch]);
        }

        f32x16 a1 = {};
        f32x16 a2 = {};
#pragma unroll
        for (int ch = 0; ch < 4; ++ch)
            a1 = __builtin_amdgcn_mfma_f32_32x32x16_f16(al[ch], bl_[ch], a1, 0, 0, 0);
#pragma unroll
        for (int ch = 0; ch < 4; ++ch)
            a1 = __builtin_amdgcn_mfma_f32_32x32x16_f16(al[ch], bh_[ch], a1, 0, 0, 0);
#pragma unroll
        for (int ch = 0; ch < 4; ++ch)
            a2 = __builtin_amdgcn_mfma_f32_32x32x16_f16(ah[ch], bl_[ch], a2, 0, 0, 0);
#pragma unroll
        for (int ch = 0; ch < 4; ++ch)
            a2 = __builtin_amdgcn_mfma_f32_32x32x16_f16(ah[ch], bh_[ch], a2, 0, 0, 0);

#pragma unroll
        for (int r = 0; r < 16; ++r) {
            float dist = fmaf(-2.f, a1[r] + a2[r], e2v);
            if (dist < best[r]) { best[r] = dist; bestt[r] = t; }
        }
        __syncthreads();   // this iter's reads done; prefetch drained
    }

    // ---- per-pixel argmin: butterfly over the 32 cols (lanes) --------------
    // k = t*32 + c; ascending-t strict < kept earliest k per lane; cross-lane
    // merge breaks ties toward smaller k. C layout (verified m74/m101):
    // col = lane&31, row = (r&3) + 8*(r>>2) + 4*hi.
#pragma unroll
    for (int r = 0; r < 16; ++r) {
        float bv = best[r];
        int   bk = (bestt[r] << 5) + c;
#pragma unroll
        for (int m = 1; m < 32; m <<= 1) {
            float ov = __shfl_xor(bv, m, 64);
            int   ok = __shfl_xor(bk, m, 64);
            if (ov < bv || (ov == bv && ok < bk)) { bv = ov; bk = ok; }
        }
        if (c == 0) {
            const int row = (r & 3) + 8 * (r >> 2) + 4 * hi;
            samin[pxb + row] = bk;
        }
    }
    __syncthreads();

    if (tx < 128) outidx[n0 + tx] = (float)samin[tx];

    // ---- gather exact fp32 codebook rows -> output, coalesced over p -------
    const int p = tx & 127;
    const int drow = tx >> 7;                 // 0 or 1
    const int amin = samin[p];
    float* obase = outq + bb * 262144 + hw + p;
#pragma unroll
    for (int it = 0; it < 32; ++it) {
        int d = (it << 1) + drow;
        obase[d * 4096] = emb[d * 1024 + amin];
    }
}

extern "C" void kernel_launch(void* const* d_in, const int* in_sizes, int n_in,
                              void* d_out, int out_size, void* d_ws, size_t ws_size,
                              hipStream_t stream) {
    const float* x   = (const float*)d_in[0];
    const float* emb = (const float*)d_in[1];
    float* outq   = (float*)d_out;
    float* outidx = outq + 8388608;            // 32*64*64*64

    float*    e2  = (float*)d_ws;                               // 4 KB
    _Float16* eTh = (_Float16*)((char*)d_ws + 4096);            // 128 KB
    _Float16* eTl = (_Float16*)((char*)d_ws + 4096 + 131072);   // 128 KB

    prep_kernel<<<16, 64, 0, stream>>>(emb, e2, eTh, eTl);
    vq_kernel<<<1024, 256, 0, stream>>>(x, eTh, eTl, e2, emb, outq, outidx);
}

// Round 5
// 158.055 us; speedup vs baseline: 1.3302x; 1.1307x over previous
//
#include <hip/hip_runtime.h>

// x [32,64,64,64] f32, emb [64,1024] f32
// N = 131072 pixels, D = 64, K = 1024
// out = [ result: 8388608 f32 ][ argmin-as-f32: 131072 ]
//
// Round 9: R8's 32x32x16 split-f16 math (verified absmax 0.0), occupancy
// unlocked:
//  - x-LDS tile DELETED: in the M-split layout each x element is used by
//    exactly ONE lane, so staging bought zero reuse. A-fragments load
//    straight from global (same coalesced f32 loads + identical h/l
//    conversion -> bit-identical values). LDS 53.8 -> 16.9 KB.
//  - single chained f32x16 accumulator (R8 proved order freedom): saves
//    16 regs + 16 v_add/iter.
//  - __launch_bounds__(256,4): cap 128 VGPR -> 4 blocks/CU (16 waves/CU,
//    was 7.3). R6-R8 showed ~2 waves/SIMD exposes every barrier/latency
//    gap; this is the latency-hiding fix.
//  - B staged in LDS via global_load_lds(16B), double-buffered, shared by
//    all 4 waves; pre-swizzled source + swizzled ds_read_b128 (verified).

using half8  = __attribute__((ext_vector_type(8))) _Float16;
using f32x16 = __attribute__((ext_vector_type(16))) float;

__global__ void prep_kernel(const float* __restrict__ emb,
                            float* __restrict__ e2,
                            _Float16* __restrict__ eTh,
                            _Float16* __restrict__ eTl) {
    int k = blockIdx.x * 64 + threadIdx.x;   // 16 blocks x 64
    float s = 0.f;
#pragma unroll
    for (int c = 0; c < 8; ++c) {
        half8 hv, lv;
#pragma unroll
        for (int j = 0; j < 8; ++j) {
            float v = emb[(c * 8 + j) * 1024 + k];   // coalesced across lanes
            s = fmaf(v, v, s);                       // ascending-d fmaf
            _Float16 h = (_Float16)v;
            hv[j] = h;
            lv[j] = (_Float16)(v - (float)h);        // exact residual
        }
        *(half8*)(eTh + k * 64 + c * 8) = hv;
        *(half8*)(eTl + k * 64 + c * 8) = lv;
    }
    e2[k] = s;
}

__launch_bounds__(256, 4)
__global__ void vq_kernel(const float* __restrict__ x,
                          const _Float16* __restrict__ eTh,
                          const _Float16* __restrict__ eTl,
                          const float* __restrict__ e2,
                          const float* __restrict__ emb,
                          float* __restrict__ outq,
                          float* __restrict__ outidx) {
    __shared__ __align__(16) _Float16 sB[2][4096];  // [buf][h:2048 | l:2048]
    __shared__ int samin[128];

    const int tx = threadIdx.x;
    const int n0 = blockIdx.x * 128;
    const int bb = n0 >> 12;
    const int hw = n0 & 4095;
    const float* xbase = x + bb * 262144 + hw;

    const int lane = tx & 63;
    const int w    = tx >> 6;
    const int c    = lane & 31;    // 32x32 col / A-row
    const int hi   = lane >> 5;    // k-half selector
    const int pxb  = w << 5;       // wave's 32-pixel base

    // ---- A-fragments straight from global: row = pxb+c, d = ch*16+hi*8+j ---
    // Same f32 values and same h/l split ops as the old LDS-staged path.
    half8 ah[4], al[4];
#pragma unroll
    for (int ch = 0; ch < 4; ++ch) {
#pragma unroll
        for (int j = 0; j < 8; ++j) {
            float v = xbase[(ch * 16 + hi * 8 + j) * 4096 + pxb + c];
            _Float16 h = (_Float16)v;
            ah[ch][j] = h;
            al[ch][j] = (_Float16)(v - (float)h);
        }
    }
    asm volatile("" ::: "memory");   // keep fragments register-resident

    // ---- swizzled LDS read offsets for B (invariant over t) ----------------
    int Dofs[4];
#pragma unroll
    for (int ch = 0; ch < 4; ++ch) {
        const int y = c * 128 + ch * 32 + hi * 16;
        Dofs[ch] = y ^ ((c & 7) << 4);
    }

    // ---- staging source: pre-swizzled per-thread global byte offset --------
    const int Lb = tx * 16;                        // linear byte in 4KB tile
    const int Sb = Lb ^ (((Lb >> 7) & 7) << 4);    // sigma (self-inverse)
    const char* gH = (const char*)eTh + Sb;
    const char* gL = (const char*)eTl + Sb;

#define STAGE(BUF, TT)                                                        \
    {                                                                         \
        __builtin_amdgcn_global_load_lds(                                     \
            (const __attribute__((address_space(1))) unsigned int*)(gH + ((TT) << 12)), \
            (__attribute__((address_space(3))) unsigned int*)(sB[BUF] + (w << 9)),       \
            16, 0, 0);                                                        \
        __builtin_amdgcn_global_load_lds(                                     \
            (const __attribute__((address_space(1))) unsigned int*)(gL + ((TT) << 12)), \
            (__attribute__((address_space(3))) unsigned int*)(sB[BUF] + 2048 + (w << 9)),\
            16, 0, 0);                                                        \
    }

    float best[16];
    int   bestt[16];
#pragma unroll
    for (int i = 0; i < 16; ++i) { best[i] = 3.4e38f; bestt[i] = 0; }

    STAGE(0, 0);
    __syncthreads();   // drains vmcnt(0): buf0 ready

#pragma unroll 1
    for (int t = 0; t < 32; ++t) {
        const int cur = t & 1;
        if (t < 31) STAGE(cur ^ 1, t + 1);        // prefetch next tile

        const float e2v = e2[(t << 5) + c];
        const char* bbase = (const char*)sB[cur];
        half8 bh_[4], bl_[4];
#pragma unroll
        for (int ch = 0; ch < 4; ++ch) {
            bh_[ch] = *(const half8*)(bbase + Dofs[ch]);
            bl_[ch] = *(const half8*)(bbase + 4096 + Dofs[ch]);
        }

        f32x16 a = {};
#pragma unroll
        for (int ch = 0; ch < 4; ++ch)
            a = __builtin_amdgcn_mfma_f32_32x32x16_f16(al[ch], bl_[ch], a, 0, 0, 0);
#pragma unroll
        for (int ch = 0; ch < 4; ++ch)
            a = __builtin_amdgcn_mfma_f32_32x32x16_f16(al[ch], bh_[ch], a, 0, 0, 0);
#pragma unroll
        for (int ch = 0; ch < 4; ++ch)
            a = __builtin_amdgcn_mfma_f32_32x32x16_f16(ah[ch], bl_[ch], a, 0, 0, 0);
#pragma unroll
        for (int ch = 0; ch < 4; ++ch)
            a = __builtin_amdgcn_mfma_f32_32x32x16_f16(ah[ch], bh_[ch], a, 0, 0, 0);

#pragma unroll
        for (int r = 0; r < 16; ++r) {
            float dist = fmaf(-2.f, a[r], e2v);
            if (dist < best[r]) { best[r] = dist; bestt[r] = t; }
        }
        __syncthreads();   // this iter's reads done; prefetch drained
    }

    // ---- per-pixel argmin: butterfly over the 32 cols (lanes) --------------
    // k = t*32 + c; ascending-t strict < kept earliest k per lane; cross-lane
    // merge breaks ties toward smaller k. C layout (verified m74/m101):
    // col = lane&31, row = (r&3) + 8*(r>>2) + 4*hi.
#pragma unroll
    for (int r = 0; r < 16; ++r) {
        float bv = best[r];
        int   bk = (bestt[r] << 5) + c;
#pragma unroll
        for (int m = 1; m < 32; m <<= 1) {
            float ov = __shfl_xor(bv, m, 64);
            int   ok = __shfl_xor(bk, m, 64);
            if (ov < bv || (ov == bv && ok < bk)) { bv = ov; bk = ok; }
        }
        if (c == 0) {
            const int row = (r & 3) + 8 * (r >> 2) + 4 * hi;
            samin[pxb + row] = bk;
        }
    }
    __syncthreads();

    if (tx < 128) outidx[n0 + tx] = (float)samin[tx];

    // ---- gather exact fp32 codebook rows -> output, coalesced over p -------
    const int p = tx & 127;
    const int drow = tx >> 7;                 // 0 or 1
    const int amin = samin[p];
    float* obase = outq + bb * 262144 + hw + p;
#pragma unroll
    for (int it = 0; it < 32; ++it) {
        int d = (it << 1) + drow;
        obase[d * 4096] = emb[d * 1024 + amin];
    }
}

extern "C" void kernel_launch(void* const* d_in, const int* in_sizes, int n_in,
                              void* d_out, int out_size, void* d_ws, size_t ws_size,
                              hipStream_t stream) {
    const float* x   = (const float*)d_in[0];
    const float* emb = (const float*)d_in[1];
    float* outq   = (float*)d_out;
    float* outidx = outq + 8388608;            // 32*64*64*64

    float*    e2  = (float*)d_ws;                               // 4 KB
    _Float16* eTh = (_Float16*)((char*)d_ws + 4096);            // 128 KB
    _Float16* eTl = (_Float16*)((char*)d_ws + 4096 + 131072);   // 128 KB

    prep_kernel<<<16, 64, 0, stream>>>(emb, e2, eTh, eTl);
    vq_kernel<<<1024, 256, 0, stream>>>(x, eTh, eTl, e2, emb, outq, outidx);
}